// Round 2
// baseline (1617.756 us; speedup 1.0000x reference)
//
#include <hip/hip_runtime.h>
#include <math.h>

#define VOCAB 50257
#define NCLS 20
#define BATCH 128
#define TLEN 2048

typedef float v8f __attribute__((ext_vector_type(8)));

// Static device scratch (rewritten fully every call; graph-capture safe).
// P layout: [dir][v][lane][4] = {xr + bihr + bhhr, xz + bihz + bhhz, xn + bihn, pad}
__device__ float g_P[(size_t)2 * VOCAB * 256];   // 103 MB
__device__ float g_feats[BATCH * 256];

__device__ __forceinline__ float fsigmoid(float x) {
    return __builtin_amdgcn_rcpf(1.f + __expf(-x));
}
__device__ __forceinline__ float ftanh(float x) {
    float e = __expf(2.f * x);
    return 1.f - 2.f * __builtin_amdgcn_rcpf(e + 1.f);
}
__device__ __forceinline__ float hsum8(v8f a) {
    float s0 = a[0] + a[4], s1 = a[1] + a[5], s2 = a[2] + a[6], s3 = a[3] + a[7];
    return (s0 + s2) + (s1 + s3);
}

// 8 named v8f values (64 floats) — SSA, guaranteed VGPR-resident (no arrays, no SROA risk)
#define DECL_W8(P, base) \
    const v8f P##0 = ((const v8f*)(base))[0], P##1 = ((const v8f*)(base))[1], \
              P##2 = ((const v8f*)(base))[2], P##3 = ((const v8f*)(base))[3], \
              P##4 = ((const v8f*)(base))[4], P##5 = ((const v8f*)(base))[5], \
              P##6 = ((const v8f*)(base))[6], P##7 = ((const v8f*)(base))[7];

// acc = sum_k H_k * W_k  (mul + 7 fma, single accumulator chain)
#define DOT8(ACC, H, W) \
    v8f ACC = H##0 * W##0; \
    ACC = __builtin_elementwise_fma(H##1, W##1, ACC); \
    ACC = __builtin_elementwise_fma(H##2, W##2, ACC); \
    ACC = __builtin_elementwise_fma(H##3, W##3, ACC); \
    ACC = __builtin_elementwise_fma(H##4, W##4, ACC); \
    ACC = __builtin_elementwise_fma(H##5, W##5, ACC); \
    ACC = __builtin_elementwise_fma(H##6, W##6, ACC); \
    ACC = __builtin_elementwise_fma(H##7, W##7, ACC);

// ---------------- Kernel A: P[dir][v][lane] = {emb[v]·wih_r + br', emb[v]·wih_z + bz', emb[v]·wih_n + bn_ih, 0}
__global__ __launch_bounds__(128, 1) void precompute_P(
    const float* __restrict__ emb,
    const float* __restrict__ wih_f, const float* __restrict__ bih_f, const float* __restrict__ bhh_f,
    const float* __restrict__ wih_b, const float* __restrict__ bih_b, const float* __restrict__ bhh_b)
{
    const int lane = threadIdx.x & 63;
    const int dir  = threadIdx.x >> 6;          // wave-uniform
    const float* wih = dir ? wih_b : wih_f;
    const float* bih = dir ? bih_b : bih_f;
    const float* bhh = dir ? bhh_b : bhh_f;

    DECL_W8(wr, wih + (size_t)lane * 64)
    DECL_W8(wz, wih + (size_t)(64 + lane) * 64)
    DECL_W8(wn, wih + (size_t)(128 + lane) * 64)
    const float br = bih[lane] + bhh[lane];            // fold bhh_r / bhh_z here
    const float bz = bih[64 + lane] + bhh[64 + lane];
    const float bn = bih[128 + lane];                  // bhh_n must stay separate (scaled by r)

    float4* Pd = (float4*)g_P + (size_t)dir * VOCAB * 64;

    for (int v = blockIdx.x; v < VOCAB; v += gridDim.x) {
        const v8f* e8 = (const v8f*)(emb + (size_t)v * 64);   // wave-uniform -> scalar loads
        const v8f h0 = e8[0], h1 = e8[1], h2 = e8[2], h3 = e8[3],
                  h4 = e8[4], h5 = e8[5], h6 = e8[6], h7 = e8[7];
        DOT8(ar, h, wr)
        DOT8(az, h, wz)
        DOT8(an, h, wn)
        float4 o;
        o.x = hsum8(ar) + br;
        o.y = hsum8(az) + bz;
        o.z = hsum8(an) + bn;
        o.w = 0.f;
        Pd[(size_t)v * 64 + lane] = o;                 // 64 lanes x 16B contiguous
    }
}

// ---------------- Kernel B: one wave per (dir,batch); 4-deep xg prefetch; fused pooling
__global__ __launch_bounds__(64, 1) void gru_seq(
    const int* __restrict__ tokens,
    const float* __restrict__ whh_f, const float* __restrict__ bhh_f,
    const float* __restrict__ whh_b, const float* __restrict__ bhh_b)
{
    const int lane = threadIdx.x;                 // hidden unit
    const int b = blockIdx.x >> 1;
    const int dir = blockIdx.x & 1;
    const float* whh = dir ? whh_b : whh_f;
    const float* bhh = dir ? bhh_b : bhh_f;
    const float4* P4 = (const float4*)g_P + (size_t)dir * VOCAB * 64;

    __shared__ __align__(32) float h_lds[64];
    __shared__ int tok_lds[TLEN];
    for (int t = lane; t < TLEN; t += 64) tok_lds[t] = tokens[b * TLEN + t];

    // recurrent weights: 192 floats in 24 named v8f (VGPR-resident by construction)
    DECL_W8(wr, whh + (size_t)lane * 64)
    DECL_W8(wz, whh + (size_t)(64 + lane) * 64)
    DECL_W8(wn, whh + (size_t)(128 + lane) * 64)
    const float bn = bhh[128 + lane];

    h_lds[lane] = 0.f;
    float h = 0.f, sum = 0.f, mx = -INFINITY;
    __syncthreads();

    auto rowAt = [&](int s) -> const float4* {
        int ss = s < TLEN ? s : TLEN - 1;               // clamp tail prefetches (values unused)
        int tok = tok_lds[dir ? (TLEN - 1 - ss) : ss];
        return P4 + (size_t)tok * 64;
    };

    float4 xg0 = rowAt(0)[lane], xg1 = rowAt(1)[lane],
           xg2 = rowAt(2)[lane], xg3 = rowAt(3)[lane];

    for (int s = 0; s < TLEN; s += 4) {
#pragma unroll
        for (int j = 0; j < 4; j++) {
            const float4 cur = (j == 0) ? xg0 : (j == 1) ? xg1 : (j == 2) ? xg2 : xg3;
            // prefetch step s+j+4: consumed 4 sub-steps (~1200 cyc) later -> covers HBM latency
            const float4 nxt = rowAt(s + j + 4)[lane];

            const v8f* hp = (const v8f*)h_lds;          // broadcast reads, conflict-free
            const v8f h0 = hp[0], h1 = hp[1], h2 = hp[2], h3 = hp[3],
                      h4 = hp[4], h5 = hp[5], h6 = hp[6], h7 = hp[7];
            DOT8(ar, h, wr)
            DOT8(az, h, wz)
            DOT8(an, h, wn)
            const float hr = hsum8(ar), hz = hsum8(az), hn = hsum8(an);

            const float r = fsigmoid(cur.x + hr);       // biases pre-folded into P
            const float z = fsigmoid(cur.y + hz);
            const float n = ftanh(cur.z + r * (hn + bn));
            h = fmaf(z, h - n, n);                      // (1-z)*n + z*h
            sum += h;
            mx = fmaxf(mx, h);

            __syncthreads();                            // single-wave: elided to lgkm wait
            h_lds[lane] = h;
            __syncthreads();

            if (j == 0) xg0 = nxt; else if (j == 1) xg1 = nxt;
            else if (j == 2) xg2 = nxt; else xg3 = nxt;
        }
    }

    g_feats[b * 256 + dir * 64 + lane] = sum * (1.f / TLEN);
    g_feats[b * 256 + 128 + dir * 64 + lane] = mx;
}

// ---------------- Kernel C: classifier  out = W2 @ gelu(W1 @ feats + b1) + b2
__global__ __launch_bounds__(64) void classifier(
    const float* __restrict__ w1, const float* __restrict__ b1,
    const float* __restrict__ w2, const float* __restrict__ b2,
    float* __restrict__ out)
{
    const int b = blockIdx.x;
    const int i = threadIdx.x;
    __shared__ float f[256];
    __shared__ float hid[64];
    for (int c = i; c < 256; c += 64) f[c] = g_feats[b * 256 + c];
    __syncthreads();

    float acc = b1[i];
    const float* wrow = w1 + (size_t)i * 256;
#pragma unroll 16
    for (int c = 0; c < 256; c++) acc = fmaf(f[c], wrow[c], acc);
    hid[i] = acc * 0.5f * (1.f + erff(acc * 0.70710678118654752f));   // exact GELU
    __syncthreads();

    if (i < NCLS) {
        float o = b2[i];
        const float* w2r = w2 + (size_t)i * 64;
#pragma unroll
        for (int j = 0; j < 64; j++) o = fmaf(hid[j], w2r[j], o);
        out[b * NCLS + i] = o;
    }
}

extern "C" void kernel_launch(void* const* d_in, const int* in_sizes, int n_in,
                              void* d_out, int out_size, void* d_ws, size_t ws_size,
                              hipStream_t stream) {
    const int*   tokens = (const int*)  d_in[0];
    const float* emb    = (const float*)d_in[1];
    const float* wih_f  = (const float*)d_in[2];
    const float* whh_f  = (const float*)d_in[3];
    const float* bih_f  = (const float*)d_in[4];
    const float* bhh_f  = (const float*)d_in[5];
    const float* wih_b  = (const float*)d_in[6];
    const float* whh_b  = (const float*)d_in[7];
    const float* bih_b  = (const float*)d_in[8];
    const float* bhh_b  = (const float*)d_in[9];
    const float* w1     = (const float*)d_in[10];
    const float* b1     = (const float*)d_in[11];
    const float* w2     = (const float*)d_in[12];
    const float* b2     = (const float*)d_in[13];
    float* out = (float*)d_out;

    precompute_P<<<512, 128, 0, stream>>>(emb, wih_f, bih_f, bhh_f, wih_b, bih_b, bhh_b);
    gru_seq<<<2 * BATCH, 64, 0, stream>>>(tokens, whh_f, bhh_f, whh_b, bhh_b);
    classifier<<<BATCH, 64, 0, stream>>>(w1, b1, w2, b2, out);
}

// Round 3
// 1264.850 us; speedup vs baseline: 1.2790x; 1.2790x over previous
//
#include <hip/hip_runtime.h>
#include <math.h>

#define VOCAB 50257
#define NCLS 20
#define BATCH 128
#define TLEN 2048

typedef float v8f __attribute__((ext_vector_type(8)));

// Static device scratch (rewritten fully every call; graph-capture safe).
// P layout: [dir][v][lane][4] = {xr + bihr + bhhr, xz + bihz + bhhz, xn + bihn, pad}
__device__ float g_P[(size_t)2 * VOCAB * 256];   // 103 MB
__device__ float g_feats[BATCH * 256];

__device__ __forceinline__ float fsigmoid(float x) {
    return __builtin_amdgcn_rcpf(1.f + __expf(-x));
}
__device__ __forceinline__ float ftanh(float x) {
    float e = __expf(2.f * x);
    return 1.f - 2.f * __builtin_amdgcn_rcpf(e + 1.f);
}
__device__ __forceinline__ float hsum8(v8f a) {
    float s0 = a[0] + a[4], s1 = a[1] + a[5], s2 = a[2] + a[6], s3 = a[3] + a[7];
    return (s0 + s2) + (s1 + s3);
}

#define DECL_W8(P, base) \
    const v8f P##0 = ((const v8f*)(base))[0], P##1 = ((const v8f*)(base))[1], \
              P##2 = ((const v8f*)(base))[2], P##3 = ((const v8f*)(base))[3], \
              P##4 = ((const v8f*)(base))[4], P##5 = ((const v8f*)(base))[5], \
              P##6 = ((const v8f*)(base))[6], P##7 = ((const v8f*)(base))[7];

#define DOT8(ACC, H, W) \
    v8f ACC = H##0 * W##0; \
    ACC = __builtin_elementwise_fma(H##1, W##1, ACC); \
    ACC = __builtin_elementwise_fma(H##2, W##2, ACC); \
    ACC = __builtin_elementwise_fma(H##3, W##3, ACC); \
    ACC = __builtin_elementwise_fma(H##4, W##4, ACC); \
    ACC = __builtin_elementwise_fma(H##5, W##5, ACC); \
    ACC = __builtin_elementwise_fma(H##6, W##6, ACC); \
    ACC = __builtin_elementwise_fma(H##7, W##7, ACC);

// ---------------- Kernel A: P[dir][v][lane] = {emb[v]·wih_r + br', emb[v]·wih_z + bz', emb[v]·wih_n + bn_ih, 0}
__global__ __launch_bounds__(128)
__attribute__((amdgpu_waves_per_eu(1, 1)))
void precompute_P(
    const float* __restrict__ emb,
    const float* __restrict__ wih_f, const float* __restrict__ bih_f, const float* __restrict__ bhh_f,
    const float* __restrict__ wih_b, const float* __restrict__ bih_b, const float* __restrict__ bhh_b)
{
    const int lane = threadIdx.x & 63;
    const int dir  = threadIdx.x >> 6;          // wave-uniform
    const float* wih = dir ? wih_b : wih_f;
    const float* bih = dir ? bih_b : bih_f;
    const float* bhh = dir ? bhh_b : bhh_f;

    DECL_W8(wr, wih + (size_t)lane * 64)
    DECL_W8(wz, wih + (size_t)(64 + lane) * 64)
    DECL_W8(wn, wih + (size_t)(128 + lane) * 64)
    const float br = bih[lane] + bhh[lane];            // fold bhh_r / bhh_z here
    const float bz = bih[64 + lane] + bhh[64 + lane];
    const float bn = bih[128 + lane];                  // bhh_n stays separate (scaled by r)

    float4* Pd = (float4*)g_P + (size_t)dir * VOCAB * 64;

    for (int v = blockIdx.x; v < VOCAB; v += gridDim.x) {
        const v8f* e8 = (const v8f*)(emb + (size_t)v * 64);   // wave-uniform -> scalar loads
        const v8f h0 = e8[0], h1 = e8[1], h2 = e8[2], h3 = e8[3],
                  h4 = e8[4], h5 = e8[5], h6 = e8[6], h7 = e8[7];
        DOT8(ar, h, wr)
        DOT8(az, h, wz)
        DOT8(an, h, wn)
        float4 o;
        o.x = hsum8(ar) + br;
        o.y = hsum8(az) + bz;
        o.z = hsum8(an) + bn;
        o.w = 0.f;
        Pd[(size_t)v * 64 + lane] = o;                 // 64 lanes x 16B contiguous
    }
}

// ---------------- Kernel B: one wave per (dir,batch); NO barriers (wave-lockstep); 4-deep prefetch
__global__ __launch_bounds__(64)
__attribute__((amdgpu_waves_per_eu(1, 1)))
void gru_seq(
    const int* __restrict__ tokens,
    const float* __restrict__ whh_f, const float* __restrict__ bhh_f,
    const float* __restrict__ whh_b, const float* __restrict__ bhh_b)
{
    const int lane = threadIdx.x;                 // hidden unit
    const int b = blockIdx.x >> 1;
    const int dir = blockIdx.x & 1;
    const float* whh = dir ? whh_b : whh_f;
    const float* bhh = dir ? bhh_b : bhh_f;
    const float4* P4 = (const float4*)g_P + (size_t)dir * VOCAB * 64;

    __shared__ __align__(32) float h_lds[64];
    __shared__ int tok_lds[TLEN];
    for (int t = lane; t < TLEN; t += 64) tok_lds[t] = tokens[b * TLEN + t];
    // single-wave block: writes by this wave are ordered before this wave's later DS reads;
    // no __syncthreads anywhere (would force a vmcnt(0) drain and kill the prefetch).

    // recurrent weights: 192 floats in 24 named v8f; amdgpu_waves_per_eu(1,1) lets the
    // allocator keep them resident (~290 VGPRs) instead of re-loading per step.
    DECL_W8(wr, whh + (size_t)lane * 64)
    DECL_W8(wz, whh + (size_t)(64 + lane) * 64)
    DECL_W8(wn, whh + (size_t)(128 + lane) * 64)
    const float bn = bhh[128 + lane];

    h_lds[lane] = 0.f;
    float h = 0.f, sum = 0.f, mx = -INFINITY;

    auto rowAt = [&](int s) -> const float4* {
        int ss = s < TLEN ? s : TLEN - 1;               // clamp tail prefetches (values unused)
        int tok = tok_lds[dir ? (TLEN - 1 - ss) : ss];
        return P4 + (size_t)tok * 64;
    };

    float4 xg[4];
#pragma unroll
    for (int j = 0; j < 4; j++) xg[j] = rowAt(j)[lane];

    for (int s = 0; s < TLEN; s += 4) {
#pragma unroll
        for (int j = 0; j < 4; j++) {
            const float4 cur = xg[j];
            // prefetch step s+j+4: loads directly into xg[j]'s register; its vmcnt wait
            // lands before next outer iteration's use -> ~4-step (>1200 cyc) cover.
            xg[j] = rowAt(s + j + 4)[lane];

            const v8f* hp = (const v8f*)h_lds;          // uniform-address reads = broadcast
            const v8f h0 = hp[0], h1 = hp[1], h2 = hp[2], h3 = hp[3],
                      h4 = hp[4], h5 = hp[5], h6 = hp[6], h7 = hp[7];
            DOT8(ar, h, wr)
            DOT8(az, h, wz)
            DOT8(an, h, wn)
            const float hr = hsum8(ar), hz = hsum8(az), hn = hsum8(an);

            const float r = fsigmoid(cur.x + hr);       // biases pre-folded into P
            const float z = fsigmoid(cur.y + hz);
            const float n = ftanh(cur.z + r * (hn + bn));
            h = fmaf(z, h - n, n);                      // (1-z)*n + z*h
            sum += h;
            mx = fmaxf(mx, h);

            __builtin_amdgcn_wave_barrier();            // scheduling fence only (no s_barrier)
            h_lds[lane] = h;
            __builtin_amdgcn_wave_barrier();
        }
    }

    g_feats[b * 256 + dir * 64 + lane] = sum * (1.f / TLEN);
    g_feats[b * 256 + 128 + dir * 64 + lane] = mx;
}

// ---------------- Kernel C: classifier  out = W2 @ gelu(W1 @ feats + b1) + b2
__global__ __launch_bounds__(64) void classifier(
    const float* __restrict__ w1, const float* __restrict__ b1,
    const float* __restrict__ w2, const float* __restrict__ b2,
    float* __restrict__ out)
{
    const int b = blockIdx.x;
    const int i = threadIdx.x;
    __shared__ float f[256];
    __shared__ float hid[64];
    for (int c = i; c < 256; c += 64) f[c] = g_feats[b * 256 + c];
    __syncthreads();

    float acc = b1[i];
    const float* wrow = w1 + (size_t)i * 256;
#pragma unroll 16
    for (int c = 0; c < 256; c++) acc = fmaf(f[c], wrow[c], acc);
    hid[i] = acc * 0.5f * (1.f + erff(acc * 0.70710678118654752f));   // exact GELU
    __syncthreads();

    if (i < NCLS) {
        float o = b2[i];
        const float* w2r = w2 + (size_t)i * 64;
#pragma unroll
        for (int j = 0; j < 64; j++) o = fmaf(hid[j], w2r[j], o);
        out[b * NCLS + i] = o;
    }
}

extern "C" void kernel_launch(void* const* d_in, const int* in_sizes, int n_in,
                              void* d_out, int out_size, void* d_ws, size_t ws_size,
                              hipStream_t stream) {
    const int*   tokens = (const int*)  d_in[0];
    const float* emb    = (const float*)d_in[1];
    const float* wih_f  = (const float*)d_in[2];
    const float* whh_f  = (const float*)d_in[3];
    const float* bih_f  = (const float*)d_in[4];
    const float* bhh_f  = (const float*)d_in[5];
    const float* wih_b  = (const float*)d_in[6];
    const float* whh_b  = (const float*)d_in[7];
    const float* bih_b  = (const float*)d_in[8];
    const float* bhh_b  = (const float*)d_in[9];
    const float* w1     = (const float*)d_in[10];
    const float* b1     = (const float*)d_in[11];
    const float* w2     = (const float*)d_in[12];
    const float* b2     = (const float*)d_in[13];
    float* out = (float*)d_out;

    precompute_P<<<1024, 128, 0, stream>>>(emb, wih_f, bih_f, bhh_f, wih_b, bih_b, bhh_b);
    gru_seq<<<2 * BATCH, 64, 0, stream>>>(tokens, whh_f, bhh_f, whh_b, bhh_b);
    classifier<<<BATCH, 64, 0, stream>>>(w1, b1, w2, b2, out);
}